// Round 1
// baseline (4507.616 us; speedup 1.0000x reference)
//
#include <hip/hip_runtime.h>
#include <cstddef>

#define Bv 4
#define Nv 24
#define NTv 16
#define Tv 64
#define NP 25
#define NEGF (-1e30f)

// ws layout (floats):
//   betaA  [B][25][25][16 A][24 h]     : 960000   (spans W>=2, nonterminal symbols, absolute head)
//   betau  [B][25][25][64 s]           : 160000
//   Rexp   [B][2 d][24 h][64 sL][64 sR][16 A] : 12582912 (optional, exp(rule) transposed)
#define BETAA_OFF 0
#define BETAU_OFF 960000
#define REXP_OFF  1120000
#define REXP_SIZE 12582912

// ---- exp(rule) + transpose to [b][d][h][sL][sR][A] ----
__global__ void exp_transpose_kernel(const float* __restrict__ rule, float* __restrict__ Rexp) {
  const int sL = blockIdx.x, h = blockIdx.y, b = blockIdx.z;
  const int t = threadIdx.x;           // 256 threads
  __shared__ float tile[2 * 64 * 17];  // [d][sR][A] padded
  const int A = t >> 4, sRb = t & 15;
  const float* src = rule + (size_t)((((b * NTv + A) * Nv + h) * Tv + sL) * Tv) * 2;
#pragma unroll
  for (int it = 0; it < 4; ++it) {
    int sR = it * 16 + sRb;
    float2 v = *(const float2*)(src + sR * 2);
    tile[(0 * 64 + sR) * 17 + A] = __expf(v.x);
    tile[(1 * 64 + sR) * 17 + A] = __expf(v.y);
  }
  __syncthreads();
#pragma unroll
  for (int d = 0; d < 2; ++d) {
    float* dst = Rexp + (size_t)(((b * 2 + d) * Nv + h) * Tv + sL) * Tv * NTv;
#pragma unroll
    for (int c = 0; c < 4; ++c) {
      int o = c * 256 + t;
      dst[o] = tile[(d * 64 + (o >> 4)) * 17 + (o & 15)];
    }
  }
}

// ---- width-1 betau init: betau[b][k][k+1][s] = unary[b][k][s] for terminal s ----
__global__ void init_betau_kernel(const float* __restrict__ unary, float* __restrict__ betau) {
  int t = blockIdx.x * blockDim.x + threadIdx.x;
  if (t >= Bv * Nv * 48) return;
  int i = t % 48, k = (t / 48) % Nv, b = t / (48 * Nv);
  int s = 16 + i;
  betau[(size_t)((b * NP + k) * NP + (k + 1)) * Tv + s] = unary[(b * Nv + k) * Tv + s];
}

// ---- one DP width step; block per (b, l), 768 threads: 2 lanes per (A, head) ----
template <bool UR>
__global__ __launch_bounds__(768) void width_kernel(
    const float* __restrict__ unary, const float* __restrict__ rule,
    const float* __restrict__ Rexp, float* __restrict__ betaA,
    float* __restrict__ betau, int W) {
  const int l = blockIdx.x, b = blockIdx.y;
  const int r = l + W;
  const int tid = threadIdx.x;   // 0..767
  const int sub = tid & 1;       // sL-loop half
  const int pid = tid >> 1;      // 0..383
  const int A = pid & 15;
  const int hh = pid >> 4;       // head offset in span, 0..23
  const int h = l + hh;
  const bool act = (hh < W);
  const int sA = tid & 15, sH = tid >> 4;  // staging mapping (tid<384)

  __shared__ float sER0[48], sEL1[48];     // exp'd (or shifted-log) betau vectors
  __shared__ float sCL0[16 * 24], sCR1[16 * 24];  // exp'd chart fragments [s][hh]
  __shared__ float sMaxL0[24], sMaxR1[24];
  __shared__ float sShR0, sShL1;
  __shared__ float sTmp[16 * 24];

  float runM = NEGF, runS = 0.f;  // online lse state

  for (int m = l + 1; m < r; ++m) {
    const int wl = m - l, wr = r - m;
    // ---------- staging ----------
    if (tid < 64) {  // dir0 right side: betau[b][m][r][*]
      const int n = (wr == 1) ? 48 : 16, s0 = (wr == 1) ? 16 : 0;
      float v = (tid < n) ? betau[(size_t)((b * NP + m) * NP + r) * Tv + s0 + tid] : NEGF;
      float mx = v;
#pragma unroll
      for (int off = 32; off; off >>= 1) mx = fmaxf(mx, __shfl_xor(mx, off, 64));
      if (tid == 0) sShR0 = mx;
      if (tid < n) sER0[tid] = UR ? __expf(v - mx) : (v - mx);
    } else if (tid < 128) {  // dir1 left side: betau[b][l][m][*]
      const int j = tid - 64;
      const int n = (wl == 1) ? 48 : 16, s0 = (wl == 1) ? 16 : 0;
      float v = (j < n) ? betau[(size_t)((b * NP + l) * NP + m) * Tv + s0 + j] : NEGF;
      float mx = v;
#pragma unroll
      for (int off = 32; off; off >>= 1) mx = fmaxf(mx, __shfl_xor(mx, off, 64));
      if (j == 0) sShL1 = mx;
      if (j < n) sEL1[j] = UR ? __expf(v - mx) : (v - mx);
    }
    if (tid < 384) {
      if (wl > 1 && sH < wl) {  // dir0 left chart betaA[b][l][m][sA][l+sH]
        float v = betaA[(size_t)((b * NP + l) * NP + m) * 384 + sA * Nv + (l + sH)];
        float mx = v;
#pragma unroll
        for (int off = 8; off; off >>= 1) mx = fmaxf(mx, __shfl_xor(mx, off, 16));
        if (sA == 0) sMaxL0[sH] = mx;
        sCL0[sA * Nv + sH] = UR ? __expf(v - mx) : (v - mx);
      }
      if (wr > 1 && sH >= wl && sH < W) {  // dir1 right chart betaA[b][m][r][sA][l+sH]
        float v = betaA[(size_t)((b * NP + m) * NP + r) * 384 + sA * Nv + (l + sH)];
        float mx = v;
#pragma unroll
        for (int off = 8; off; off >>= 1) mx = fmaxf(mx, __shfl_xor(mx, off, 16));
        if (sA == 0) sMaxR1[sH] = mx;
        sCR1[sA * Nv + sH] = UR ? __expf(v - mx) : (v - mx);
      }
    }
    __syncthreads();
    // ---------- compute ----------
    if (act) {
      if (hh < wl && (wl > 1 || hh == 0)) {  // dir0: head in left child
        const int nL = (wl == 1) ? 48 : 16, sL0 = (wl == 1) ? 16 : 0;
        const int nR = (wr == 1) ? 48 : 16, sR0 = (wr == 1) ? 16 : 0;
        const float shift = ((wl == 1) ? 0.f : sMaxL0[hh]) + sShR0;
        float part = 0.f;
        if (UR) {
          const float* rb = Rexp + (size_t)(((b * 2 + 0) * Nv + h) * Tv) * Tv * NTv + A;
          for (int i = sub; i < nL; i += 2) {
            const float cl = (wl == 1) ? 1.f : sCL0[i * Nv + hh];
            const float* rp = rb + (size_t)(sL0 + i) * Tv * NTv + sR0 * NTv;
            float acc = 0.f;
#pragma unroll 8
            for (int j = 0; j < nR; ++j) acc += sER0[j] * rp[j * NTv];
            part += cl * acc;
          }
        } else {
          const float* rb = rule + (size_t)(((b * NTv + A) * Nv + h) * Tv) * Tv * 2;
          for (int i = sub; i < nL; i += 2) {
            const float cl = (wl == 1) ? 0.f : sCL0[i * Nv + hh];
            const float* rp = rb + (size_t)(sL0 + i) * Tv * 2 + sR0 * 2;
#pragma unroll 8
            for (int j = 0; j < nR; ++j) part += __expf(cl + sER0[j] + rp[j * 2]);
          }
        }
        float nm = fmaxf(runM, shift);
        runS = runS * __expf(runM - nm) + part * __expf(shift - nm);
        runM = nm;
      }
      if (hh >= wl && (wr > 1 || hh == W - 1)) {  // dir1: head in right child
        const int nL = (wl == 1) ? 48 : 16, sL0 = (wl == 1) ? 16 : 0;
        const int nR = (wr == 1) ? 48 : 16, sR0 = (wr == 1) ? 16 : 0;
        const float shift = sShL1 + ((wr == 1) ? 0.f : sMaxR1[hh]);
        float part = 0.f;
        if (UR) {
          const float* rb = Rexp + (size_t)(((b * 2 + 1) * Nv + h) * Tv) * Tv * NTv + A;
          for (int i = sub; i < nL; i += 2) {
            const float el = sEL1[i];
            const float* rp = rb + (size_t)(sL0 + i) * Tv * NTv + sR0 * NTv;
            float acc = 0.f;
#pragma unroll 8
            for (int j = 0; j < nR; ++j) {
              const float cr = (wr == 1) ? 1.f : sCR1[j * Nv + hh];
              acc += cr * rp[j * NTv];
            }
            part += el * acc;
          }
        } else {
          const float* rb = rule + (size_t)(((b * NTv + A) * Nv + h) * Tv) * Tv * 2 + 1;
          for (int i = sub; i < nL; i += 2) {
            const float el = sEL1[i];
            const float* rp = rb + (size_t)(sL0 + i) * Tv * 2 + sR0 * 2;
#pragma unroll 8
            for (int j = 0; j < nR; ++j) {
              const float cr = (wr == 1) ? 0.f : sCR1[j * Nv + hh];
              part += __expf(el + cr + rp[j * 2]);
            }
          }
        }
        float nm = fmaxf(runM, shift);
        runS = runS * __expf(runM - nm) + part * __expf(shift - nm);
        runM = nm;
      }
    }
    __syncthreads();
  }
  // ---------- pair-merge + writes ----------
  if (act) {
    float om = __shfl_xor(runM, 1, 64);
    float os = __shfl_xor(runS, 1, 64);
    float nm = fmaxf(runM, om);
    float s = runS * __expf(runM - nm) + os * __expf(om - nm);
    if (sub == 0) {
      float val = nm + __logf(s);
      betaA[(size_t)((b * NP + l) * NP + r) * 384 + A * Nv + h] = val;
      sTmp[A * Nv + hh] = val + unary[(b * Nv + h) * Tv + A];  // + head-word unary for betau
    }
  }
  __syncthreads();
  if (tid < 16) {  // betau[b][l][r][A] = lse_h(tmp + unary)
    float mx = NEGF;
    for (int x = 0; x < W; ++x) mx = fmaxf(mx, sTmp[tid * Nv + x]);
    float s = 0.f;
    for (int x = 0; x < W; ++x) s += __expf(sTmp[tid * Nv + x] - mx);
    betau[(size_t)((b * NP + l) * NP + r) * Tv + tid] = mx + __logf(s);
  }
}

// ---- out[b] = lse_A(betau[b][0][N][A] + root[b][A]) ----
__global__ void final_kernel(const float* __restrict__ betau, const float* __restrict__ root,
                             float* __restrict__ out) {
  int b = threadIdx.x;
  if (b < Bv) {
    float vals[NTv];
    float mx = NEGF;
#pragma unroll
    for (int A = 0; A < NTv; ++A) {
      float v = betau[(size_t)((b * NP + 0) * NP + Nv) * Tv + A] + root[b * NTv + A];
      vals[A] = v;
      mx = fmaxf(mx, v);
    }
    float s = 0.f;
#pragma unroll
    for (int A = 0; A < NTv; ++A) s += __expf(vals[A] - mx);
    out[b] = mx + __logf(s);
  }
}

extern "C" void kernel_launch(void* const* d_in, const int* in_sizes, int n_in,
                              void* d_out, int out_size, void* d_ws, size_t ws_size,
                              hipStream_t stream) {
  (void)in_sizes; (void)n_in; (void)out_size;
  const float* unary = (const float*)d_in[0];
  const float* rule  = (const float*)d_in[1];
  const float* root  = (const float*)d_in[2];
  float* out = (float*)d_out;
  float* ws = (float*)d_ws;
  float* betaA = ws + BETAA_OFF;
  float* betau = ws + BETAU_OFF;
  float* Rexp  = ws + REXP_OFF;
  const bool useRexp = ws_size >= (size_t)(REXP_OFF + REXP_SIZE) * sizeof(float);

  if (useRexp)
    exp_transpose_kernel<<<dim3(64, 24, 4), 256, 0, stream>>>(rule, Rexp);
  init_betau_kernel<<<(Bv * Nv * 48 + 255) / 256, 256, 0, stream>>>(unary, betau);
  for (int W = 2; W <= Nv; ++W) {
    dim3 grid(Nv - W + 1, Bv);
    if (useRexp)
      width_kernel<true><<<grid, 768, 0, stream>>>(unary, rule, Rexp, betaA, betau, W);
    else
      width_kernel<false><<<grid, 768, 0, stream>>>(unary, rule, Rexp, betaA, betau, W);
  }
  final_kernel<<<1, 64, 0, stream>>>(betau, root, out);
}

// Round 2
// 696.597 us; speedup vs baseline: 6.4709x; 6.4709x over previous
//
#include <hip/hip_runtime.h>
#include <cstddef>

#define Bv 4
#define Nv 24
#define NTv 16
#define Tv 64
#define NP 25
#define NEGF (-1e30f)

// ---------------- workspace layout (floats) ----------------
#define BETAA_OFF 0         // [B][25][25][16 sym][24 head]        960000
#define BETAU_OFF 960000    // [B][25][25][64 sym]                 160000
#define RNT_OFF   1120000   // [B][2 d][24 h][16 sL][16 sR][16 A]  786432
#define T0_OFF    1906432   // [B][24 h][24 p][16 sL][16 A]        589824
#define T1_OFF    2496256   // [B][24 h][24 p][16 sR][16 A]        589824
#define T0L_OFF   3086080   // [B][24 p][16 sR][16 A]              24576
#define T1R_OFF   3110656   // [B][24 p][16 sL][16 A]              24576
#define D0_OFF    3135232   // [B][24 l][16 A]                     1536
#define D1_OFF    3136768   // [B][24 l][16 A]                     1536
#define WS_NEED   3138304

// v1 fallback needs 54.8MB Rexp at this offset (only used if ws is huge but < new scheme... kept for safety)
#define REXP_OFF  1120000

__device__ __forceinline__ float shflmax16(float v) {
  v = fmaxf(v, __shfl_xor(v, 8, 16));
  v = fmaxf(v, __shfl_xor(v, 4, 16));
  v = fmaxf(v, __shfl_xor(v, 2, 16));
  v = fmaxf(v, __shfl_xor(v, 1, 16));
  return v;
}

// ---- P1: RexpNT[b,d,h,sL,sR,A] = exp(rule[b,A,h,sL,sR,d]), sL,sR < 16 ----
__global__ void p1_kernel(const float* __restrict__ rule, float* __restrict__ RNT) {
  const int h = blockIdx.x, A = blockIdx.y, b = blockIdx.z;
  const int t = threadIdx.x;  // 256
  const int sL = t >> 4, sR = t & 15;
  const float* rp = rule + ((((size_t)(b * NTv + A) * Nv + h) * Tv + sL) * Tv + sR) * 2;
  float2 v = *(const float2*)rp;
  RNT[((size_t)((b * 2 + 0) * Nv + h)) * 4096 + (size_t)t * 16 + A] = __expf(v.x);
  RNT[((size_t)((b * 2 + 1) * Nv + h)) * 4096 + (size_t)t * 16 + A] = __expf(v.y);
}

// ---- P2: terminal-child precontractions ----
__global__ void p2_kernel(const float* __restrict__ rule, const float* __restrict__ unary,
                          float* __restrict__ T0, float* __restrict__ T1,
                          float* __restrict__ T0L, float* __restrict__ T1R,
                          float* __restrict__ D0, float* __restrict__ D1) {
  const int h = blockIdx.x, b = blockIdx.y;
  const int t = threadIdx.x;  // 256
  const int A = t & 15, x = t >> 4;
  __shared__ float E[24 * 48];  // exp(unary[b,p,16+j])
  __shared__ float sD[256];
  for (int idx = t; idx < 24 * 48; idx += 256)
    E[idx] = __expf(unary[(size_t)(b * Nv + idx / 48) * Tv + 16 + idx % 48]);
  __syncthreads();
  // T0[b,h,p,sL=x,A] = sum_j E[p][j]*exp(rule[b,A,h,sL,16+j,0])
  {
    const float* rp = rule + ((((size_t)(b * NTv + A) * Nv + h) * Tv + x) * Tv + 16) * 2;
    float acc[24];
#pragma unroll
    for (int p = 0; p < 24; ++p) acc[p] = 0.f;
    for (int j = 0; j < 48; ++j) {
      float rv = __expf(rp[j * 2]);
#pragma unroll
      for (int p = 0; p < 24; ++p) acc[p] += E[p * 48 + j] * rv;
    }
#pragma unroll
    for (int p = 0; p < 24; ++p)
      T0[(((size_t)(b * Nv + h) * Nv + p) * NTv + x) * NTv + A] = acc[p];
  }
  // T1[b,h,p,sR=x,A] = sum_i E[p][i]*exp(rule[b,A,h,16+i,sR,1])
  {
    const float* rp = rule + ((((size_t)(b * NTv + A) * Nv + h) * Tv + 16) * Tv + x) * 2 + 1;
    float acc[24];
#pragma unroll
    for (int p = 0; p < 24; ++p) acc[p] = 0.f;
    for (int i = 0; i < 48; ++i) {
      float rv = __expf(rp[i * 128]);
#pragma unroll
      for (int p = 0; p < 24; ++p) acc[p] += E[p * 48 + i] * rv;
    }
#pragma unroll
    for (int p = 0; p < 24; ++p)
      T1[(((size_t)(b * Nv + h) * Nv + p) * NTv + x) * NTv + A] = acc[p];
  }
  // T0L[b,h,sR=x,A] = sum_i exp(rule[b,A,h,16+i,sR,0])   (left terminal chart == 0)
  {
    const float* rp = rule + ((((size_t)(b * NTv + A) * Nv + h) * Tv + 16) * Tv + x) * 2;
    float acc = 0.f;
    for (int i = 0; i < 48; ++i) acc += __expf(rp[i * 128]);
    T0L[((size_t)(b * Nv + h) * NTv + x) * NTv + A] = acc;
  }
  // T1R[b,h,sL=x,A] = sum_j exp(rule[b,A,h,sL,16+j,1])   (right terminal chart == 0)
  {
    const float* rp = rule + ((((size_t)(b * NTv + A) * Nv + h) * Tv + x) * Tv + 16) * 2 + 1;
    float acc = 0.f;
    for (int j = 0; j < 48; ++j) acc += __expf(rp[j * 2]);
    T1R[((size_t)(b * Nv + h) * NTv + x) * NTv + A] = acc;
  }
  // D0[b,l=h,A] = sum_{i,j} E[h+1][j]*exp(rule[b,A,h,16+i,16+j,0])   (W==2, head=l)
  {
    float acc = 0.f;
    if (h <= 22) {
      for (int i = x; i < 48; i += 16) {
        const float* rp = rule + ((((size_t)(b * NTv + A) * Nv + h) * Tv + 16 + i) * Tv + 16) * 2;
        for (int j = 0; j < 48; ++j) acc += E[(h + 1) * 48 + j] * __expf(rp[j * 2]);
      }
    }
    sD[t] = acc;
    __syncthreads();
    if (x == 0 && h <= 22) {
      float s = 0.f;
      for (int k = 0; k < 16; ++k) s += sD[k * 16 + A];
      D0[(size_t)(b * Nv + h) * NTv + A] = s;
    }
    __syncthreads();
  }
  // D1[b,l=h-1,A] = sum_{i,j} E[h-1][i]*exp(rule[b,A,h,16+i,16+j,1])  (W==2, head=l+1)
  {
    float acc = 0.f;
    if (h >= 1) {
      for (int i = x; i < 48; i += 16) {
        const float* rp = rule + ((((size_t)(b * NTv + A) * Nv + h) * Tv + 16 + i) * Tv + 16) * 2 + 1;
        float inner = 0.f;
        for (int j = 0; j < 48; ++j) inner += __expf(rp[j * 2]);
        acc += E[(h - 1) * 48 + i] * inner;
      }
    }
    sD[t] = acc;
    __syncthreads();
    if (x == 0 && h >= 1) {
      float s = 0.f;
      for (int k = 0; k < 16; ++k) s += sD[k * 16 + A];
      D1[(size_t)(b * Nv + (h - 1)) * NTv + A] = s;
    }
  }
}

// ---- width-1 betau init ----
__global__ void init_betau_kernel(const float* __restrict__ unary, float* __restrict__ betau) {
  int t = blockIdx.x * blockDim.x + threadIdx.x;
  if (t >= Bv * Nv * 48) return;
  int i = t % 48, k = (t / 48) % Nv, b = t / (48 * Nv);
  betau[(size_t)((b * NP + k) * NP + (k + 1)) * Tv + 16 + i] = unary[(b * Nv + k) * Tv + 16 + i];
}

// ---- main width kernel: block per (b,l); U-trick + coalesced contraction ----
__global__ __launch_bounds__(768) void width_kernel2(
    const float* __restrict__ unary, float* __restrict__ betaA, float* __restrict__ betau,
    const float* __restrict__ RNT, const float* __restrict__ T0, const float* __restrict__ T1,
    const float* __restrict__ T0L, const float* __restrict__ T1R,
    const float* __restrict__ D0, const float* __restrict__ D1, int W) {
  const int l = blockIdx.x, b = blockIdx.y;
  const int r = l + W;
  const int tid = threadIdx.x;

  __shared__ float U0[24 * 256], U1[24 * 256];
  __shared__ float G0[24], G1[24];
  __shared__ float cL[16 * 25], cR[16 * 25], ecR[16 * 25];
  __shared__ float eL[16], eR[16], eeR[16];
  __shared__ float pM[2 * 24 * 16], pS[2 * 24 * 16];
  __shared__ float sTmp[16 * 24];

  for (int i = tid; i < 24 * 256; i += 768) { U0[i] = 0.f; U1[i] = 0.f; }
  if (tid < 24) { G0[tid] = NEGF; G1[tid] = NEGF; }
  // edge staging m=l+1 (right child (l+1,r), width W-1>=2): chart rows + betau
  if (W >= 3) {
    if (tid < 384) {
      const size_t cb = ((size_t)(b * NP + (l + 1)) * NP + r) * 384;
      int s = tid / 24, j = tid % 24, jj = j - l;
      float v = betaA[cb + s * 24 + j];
      if (jj >= 0 && jj < 24) ecR[s * 25 + jj] = v;
    } else if (tid < 400) {
      eeR[tid - 384] = betau[((size_t)(b * NP + (l + 1)) * NP + r) * Tv + (tid - 384)];
    }
  }
  __syncthreads();

  // interior splits: wl>=2 && wr>=2
  for (int m = l + 2; m <= r - 2; ++m) {
    const int wl = m - l;
    if (tid < 384) {
      const size_t cb = ((size_t)(b * NP + l) * NP + m) * 384;
      int s = tid / 24, j = tid % 24, jj = j - l;
      float v = betaA[cb + s * 24 + j];
      if (jj >= 0 && jj < 24) cL[s * 25 + jj] = v;
      if (tid < 16) eR[tid] = betau[((size_t)(b * NP + m) * NP + r) * Tv + tid];
    } else {
      const size_t cb = ((size_t)(b * NP + m) * NP + r) * 384;
      int t2 = tid - 384;
      int s = t2 / 24, j = t2 % 24, jj = j - l;
      float v = betaA[cb + s * 24 + j];
      if (jj >= 0 && jj < 24) cR[s * 25 + jj] = v;
      if (t2 < 16) eL[t2] = betau[((size_t)(b * NP + l) * NP + m) * Tv + t2];
    }
    __syncthreads();
    const int g = tid >> 5, gk = tid & 31;
    if (g < W) {
      const int d = (g < wl) ? 0 : 1;  // head g in left child -> dir0, else dir1
      const int s16 = gk & 15;
      float vL = (d == 0) ? cL[s16 * 25 + g] : eL[s16];
      float vR = (d == 0) ? eR[s16] : cR[s16 * 25 + g];
      float mL = shflmax16(vL), mR = shflmax16(vR);
      float sh = mL + mR;
      float Gold = (d == 0) ? G0[g] : G1[g];
      float Gnew = fmaxf(Gold, sh);
      float f = __expf(Gold - Gnew);
      float w0 = __expf(sh - Gnew);
      float* Urow = (d == 0 ? U0 : U1) + g * 256;
      const float eRv = w0 * __expf(((d == 0) ? eR[s16] : cR[s16 * 25 + g]) - mR);
#pragma unroll
      for (int j = 0; j < 8; ++j) {
        int e = gk + 32 * j;
        int sL = e >> 4;
        float eLv = __expf(((d == 0) ? cL[sL * 25 + g] : eL[sL]) - mL);
        Urow[e] = Urow[e] * f + eRv * eLv;
      }
      if (gk == 0) { if (d == 0) G0[g] = Gnew; else G1[g] = Gnew; }
    }
    __syncthreads();
  }

  // edge staging m=r-1 (left child (l,r-1), width W-1>=2): into cL/eL (loop done)
  if (W >= 3 && tid < 384) {
    const size_t cb = ((size_t)(b * NP + l) * NP + (r - 1)) * 384;
    int s = tid / 24, j = tid % 24, jj = j - l;
    float v = betaA[cb + s * 24 + j];
    if (jj >= 0 && jj < 24) cL[s * 25 + jj] = v;
    if (tid < 16) eL[tid] = betau[((size_t)(b * NP + l) * NP + (r - 1)) * Tv + tid];
  }
  __syncthreads();

  // ---- Phase B: per (head,dir) contraction, one wave each ----
  {
    const int w = tid >> 6, lane = tid & 63;
    const int A = lane & 15, q = lane >> 4;
    for (int p = w; p < 2 * W; p += 12) {
      const int hh = p >> 1, d = p & 1;
      const int h = l + hh;
      const float* Urow = (d == 0 ? U0 : U1) + hh * 256;
      const float* Rb = RNT + ((size_t)((b * 2 + d) * Nv + h)) * 4096;
      float a0 = 0.f, a1 = 0.f, a2 = 0.f, a3 = 0.f;
#pragma unroll
      for (int sL = 0; sL < 16; sL += 4) {
#pragma unroll
        for (int jj = 0; jj < 4; ++jj) {
          a0 += Urow[(sL + 0) * 16 + jj * 4 + q] * Rb[(sL + 0) * 256 + jj * 64 + lane];
          a1 += Urow[(sL + 1) * 16 + jj * 4 + q] * Rb[(sL + 1) * 256 + jj * 64 + lane];
          a2 += Urow[(sL + 2) * 16 + jj * 4 + q] * Rb[(sL + 2) * 256 + jj * 64 + lane];
          a3 += Urow[(sL + 3) * 16 + jj * 4 + q] * Rb[(sL + 3) * 256 + jj * 64 + lane];
        }
      }
      float Sint = (a0 + a1) + (a2 + a3);
      Sint += __shfl_xor(Sint, 16, 64);
      Sint += __shfl_xor(Sint, 32, 64);
      float Mi = (d == 0) ? G0[hh] : G1[hh];
      float sh2 = NEGF, S2 = 0.f, sh3 = NEGF, S3 = 0.f;
      if (W >= 3) {
        if (d == 0 && hh < W - 1) {  // split m=r-1: chart(l,r-1,·,h) x terminal-betau via T0
          float mx = shflmax16(cL[(lane & 15) * 25 + hh]);
          const float* Tb = T0 + ((size_t)(b * Nv + h) * Nv + (r - 1)) * 256;
          float dot = 0.f;
#pragma unroll
          for (int k = 0; k < 4; ++k) {
            int s2 = 4 * q + k;
            dot += __expf(cL[s2 * 25 + hh] - mx) * Tb[s2 * 16 + A];
          }
          dot += __shfl_xor(dot, 16, 64);
          dot += __shfl_xor(dot, 32, 64);
          sh2 = mx; S2 = dot;
        }
        if (d == 0 && hh == 0) {  // split m=l+1: terminal chart (==0) x betau(l+1,r) via T0L
          float mx = shflmax16(eeR[lane & 15]);
          const float* Tb = T0L + ((size_t)(b * Nv + l)) * 256;
          float dot = 0.f;
#pragma unroll
          for (int k = 0; k < 4; ++k) {
            int s2 = 4 * q + k;
            dot += __expf(eeR[s2] - mx) * Tb[s2 * 16 + A];
          }
          dot += __shfl_xor(dot, 16, 64);
          dot += __shfl_xor(dot, 32, 64);
          sh3 = mx; S3 = dot;
        }
        if (d == 1 && hh >= 1) {  // split m=l+1: terminal betau x chart(l+1,r,·,h) via T1
          float mx = shflmax16(ecR[(lane & 15) * 25 + hh]);
          const float* Tb = T1 + ((size_t)(b * Nv + h) * Nv + l) * 256;
          float dot = 0.f;
#pragma unroll
          for (int k = 0; k < 4; ++k) {
            int s2 = 4 * q + k;
            dot += __expf(ecR[s2 * 25 + hh] - mx) * Tb[s2 * 16 + A];
          }
          dot += __shfl_xor(dot, 16, 64);
          dot += __shfl_xor(dot, 32, 64);
          sh2 = mx; S2 = dot;
        }
        if (d == 1 && hh == W - 1) {  // split m=r-1: betau(l,r-1) x terminal chart via T1R
          float mx = shflmax16(eL[lane & 15]);
          const float* Tb = T1R + ((size_t)(b * Nv + (r - 1))) * 256;
          float dot = 0.f;
#pragma unroll
          for (int k = 0; k < 4; ++k) {
            int s2 = 4 * q + k;
            dot += __expf(eL[s2] - mx) * Tb[s2 * 16 + A];
          }
          dot += __shfl_xor(dot, 16, 64);
          dot += __shfl_xor(dot, 32, 64);
          sh3 = mx; S3 = dot;
        }
      } else {  // W == 2
        if (d == 0 && hh == 0) { sh2 = 0.f; S2 = D0[(size_t)(b * Nv + l) * NTv + A]; }
        if (d == 1 && hh == 1) { sh2 = 0.f; S2 = D1[(size_t)(b * Nv + l) * NTv + A]; }
      }
      float Mf = fmaxf(Mi, fmaxf(sh2, sh3));
      float Sf = Sint * __expf(Mi - Mf) + S2 * __expf(sh2 - Mf) + S3 * __expf(sh3 - Mf);
      if (lane < 16) {
        pM[(d * 24 + hh) * 16 + A] = Mf;
        pS[(d * 24 + hh) * 16 + A] = Sf;
      }
    }
  }
  __syncthreads();
  // combine dirs, write beta; prep betau input
  if (tid < 384) {
    int A = tid & 15, hh = tid >> 4;
    if (hh < W) {
      float M0 = pM[(0 * 24 + hh) * 16 + A], S0 = pS[(0 * 24 + hh) * 16 + A];
      float M1 = pM[(1 * 24 + hh) * 16 + A], S1 = pS[(1 * 24 + hh) * 16 + A];
      float nm = fmaxf(M0, M1);
      float s = S0 * __expf(M0 - nm) + S1 * __expf(M1 - nm);
      float val = nm + __logf(s);
      betaA[((size_t)(b * NP + l) * NP + r) * 384 + A * 24 + (l + hh)] = val;
      sTmp[A * 24 + hh] = val + unary[(size_t)(b * Nv + (l + hh)) * Tv + A];
    }
  }
  __syncthreads();
  if (tid < 16) {
    float mx = NEGF;
    for (int x = 0; x < W; ++x) mx = fmaxf(mx, sTmp[tid * 24 + x]);
    float s = 0.f;
    for (int x = 0; x < W; ++x) s += __expf(sTmp[tid * 24 + x] - mx);
    betau[((size_t)(b * NP + l) * NP + r) * Tv + tid] = mx + __logf(s);
  }
}

// ---- v1 fallback width kernel (direct rule reads), used only if ws too small ----
__global__ __launch_bounds__(768) void width_kernel_fb(
    const float* __restrict__ unary, const float* __restrict__ rule,
    float* __restrict__ betaA, float* __restrict__ betau, int W) {
  const int l = blockIdx.x, b = blockIdx.y;
  const int r = l + W;
  const int tid = threadIdx.x;
  const int sub = tid & 1;
  const int pid = tid >> 1;
  const int A = pid & 15;
  const int hh = pid >> 4;
  const int h = l + hh;
  const bool act = (hh < W);
  const int sA = tid & 15, sH = tid >> 4;

  __shared__ float sER0[48], sEL1[48];
  __shared__ float sCL0[16 * 24], sCR1[16 * 24];
  __shared__ float sMaxL0[24], sMaxR1[24];
  __shared__ float sShR0, sShL1;
  __shared__ float sTmp[16 * 24];

  float runM = NEGF, runS = 0.f;
  for (int m = l + 1; m < r; ++m) {
    const int wl = m - l, wr = r - m;
    if (tid < 64) {
      const int n = (wr == 1) ? 48 : 16, s0 = (wr == 1) ? 16 : 0;
      float v = (tid < n) ? betau[(size_t)((b * NP + m) * NP + r) * Tv + s0 + tid] : NEGF;
      float mx = v;
#pragma unroll
      for (int off = 32; off; off >>= 1) mx = fmaxf(mx, __shfl_xor(mx, off, 64));
      if (tid == 0) sShR0 = mx;
      if (tid < n) sER0[tid] = v - mx;
    } else if (tid < 128) {
      const int j = tid - 64;
      const int n = (wl == 1) ? 48 : 16, s0 = (wl == 1) ? 16 : 0;
      float v = (j < n) ? betau[(size_t)((b * NP + l) * NP + m) * Tv + s0 + j] : NEGF;
      float mx = v;
#pragma unroll
      for (int off = 32; off; off >>= 1) mx = fmaxf(mx, __shfl_xor(mx, off, 64));
      if (j == 0) sShL1 = mx;
      if (j < n) sEL1[j] = v - mx;
    }
    if (tid < 384) {
      if (wl > 1 && sH < wl) {
        float v = betaA[(size_t)((b * NP + l) * NP + m) * 384 + sA * Nv + (l + sH)];
        float mx = v;
#pragma unroll
        for (int off = 8; off; off >>= 1) mx = fmaxf(mx, __shfl_xor(mx, off, 16));
        if (sA == 0) sMaxL0[sH] = mx;
        sCL0[sA * Nv + sH] = v - mx;
      }
      if (wr > 1 && sH >= wl && sH < W) {
        float v = betaA[(size_t)((b * NP + m) * NP + r) * 384 + sA * Nv + (l + sH)];
        float mx = v;
#pragma unroll
        for (int off = 8; off; off >>= 1) mx = fmaxf(mx, __shfl_xor(mx, off, 16));
        if (sA == 0) sMaxR1[sH] = mx;
        sCR1[sA * Nv + sH] = v - mx;
      }
    }
    __syncthreads();
    if (act) {
      if (hh < wl && (wl > 1 || hh == 0)) {
        const int nL = (wl == 1) ? 48 : 16, sL0 = (wl == 1) ? 16 : 0;
        const int nR = (wr == 1) ? 48 : 16, sR0 = (wr == 1) ? 16 : 0;
        const float shift = ((wl == 1) ? 0.f : sMaxL0[hh]) + sShR0;
        float part = 0.f;
        const float* rb = rule + (size_t)(((b * NTv + A) * Nv + h) * Tv) * Tv * 2;
        for (int i = sub; i < nL; i += 2) {
          const float cl = (wl == 1) ? 0.f : sCL0[i * Nv + hh];
          const float* rp = rb + (size_t)(sL0 + i) * Tv * 2 + sR0 * 2;
#pragma unroll 8
          for (int j = 0; j < nR; ++j) part += __expf(cl + sER0[j] + rp[j * 2]);
        }
        float nm = fmaxf(runM, shift);
        runS = runS * __expf(runM - nm) + part * __expf(shift - nm);
        runM = nm;
      }
      if (hh >= wl && (wr > 1 || hh == W - 1)) {
        const int nL = (wl == 1) ? 48 : 16, sL0 = (wl == 1) ? 16 : 0;
        const int nR = (wr == 1) ? 48 : 16, sR0 = (wr == 1) ? 16 : 0;
        const float shift = sShL1 + ((wr == 1) ? 0.f : sMaxR1[hh]);
        float part = 0.f;
        const float* rb = rule + (size_t)(((b * NTv + A) * Nv + h) * Tv) * Tv * 2 + 1;
        for (int i = sub; i < nL; i += 2) {
          const float el = sEL1[i];
          const float* rp = rb + (size_t)(sL0 + i) * Tv * 2 + sR0 * 2;
#pragma unroll 8
          for (int j = 0; j < nR; ++j) {
            const float cr = (wr == 1) ? 0.f : sCR1[j * Nv + hh];
            part += __expf(el + cr + rp[j * 2]);
          }
        }
        float nm = fmaxf(runM, shift);
        runS = runS * __expf(runM - nm) + part * __expf(shift - nm);
        runM = nm;
      }
    }
    __syncthreads();
  }
  if (act) {
    float om = __shfl_xor(runM, 1, 64);
    float os = __shfl_xor(runS, 1, 64);
    float nm = fmaxf(runM, om);
    float s = runS * __expf(runM - nm) + os * __expf(om - nm);
    if (sub == 0) {
      float val = nm + __logf(s);
      betaA[(size_t)((b * NP + l) * NP + r) * 384 + A * Nv + h] = val;
      sTmp[A * Nv + hh] = val + unary[(b * Nv + h) * Tv + A];
    }
  }
  __syncthreads();
  if (tid < 16) {
    float mx = NEGF;
    for (int x = 0; x < W; ++x) mx = fmaxf(mx, sTmp[tid * Nv + x]);
    float s = 0.f;
    for (int x = 0; x < W; ++x) s += __expf(sTmp[tid * Nv + x] - mx);
    betau[(size_t)((b * NP + l) * NP + r) * Tv + tid] = mx + __logf(s);
  }
}

// ---- out[b] = lse_A(betau[b][0][N][A] + root[b][A]) ----
__global__ void final_kernel(const float* __restrict__ betau, const float* __restrict__ root,
                             float* __restrict__ out) {
  int b = threadIdx.x;
  if (b < Bv) {
    float vals[NTv];
    float mx = NEGF;
#pragma unroll
    for (int A = 0; A < NTv; ++A) {
      float v = betau[(size_t)((b * NP + 0) * NP + Nv) * Tv + A] + root[b * NTv + A];
      vals[A] = v;
      mx = fmaxf(mx, v);
    }
    float s = 0.f;
#pragma unroll
    for (int A = 0; A < NTv; ++A) s += __expf(vals[A] - mx);
    out[b] = mx + __logf(s);
  }
}

extern "C" void kernel_launch(void* const* d_in, const int* in_sizes, int n_in,
                              void* d_out, int out_size, void* d_ws, size_t ws_size,
                              hipStream_t stream) {
  (void)in_sizes; (void)n_in; (void)out_size;
  const float* unary = (const float*)d_in[0];
  const float* rule  = (const float*)d_in[1];
  const float* root  = (const float*)d_in[2];
  float* out = (float*)d_out;
  float* ws = (float*)d_ws;
  float* betaA = ws + BETAA_OFF;
  float* betau = ws + BETAU_OFF;
  const bool fast = ws_size >= (size_t)WS_NEED * sizeof(float);

  init_betau_kernel<<<(Bv * Nv * 48 + 255) / 256, 256, 0, stream>>>(unary, betau);
  if (fast) {
    float* RNT = ws + RNT_OFF;
    float* T0  = ws + T0_OFF;
    float* T1  = ws + T1_OFF;
    float* T0L = ws + T0L_OFF;
    float* T1R = ws + T1R_OFF;
    float* D0  = ws + D0_OFF;
    float* D1  = ws + D1_OFF;
    p1_kernel<<<dim3(24, 16, 4), 256, 0, stream>>>(rule, RNT);
    p2_kernel<<<dim3(24, 4), 256, 0, stream>>>(rule, unary, T0, T1, T0L, T1R, D0, D1);
    for (int W = 2; W <= Nv; ++W) {
      dim3 grid(Nv - W + 1, Bv);
      width_kernel2<<<grid, 768, 0, stream>>>(unary, betaA, betau, RNT, T0, T1, T0L, T1R, D0, D1, W);
    }
  } else {
    for (int W = 2; W <= Nv; ++W) {
      dim3 grid(Nv - W + 1, Bv);
      width_kernel_fb<<<grid, 768, 0, stream>>>(unary, rule, betaA, betau, W);
    }
  }
  final_kernel<<<1, 64, 0, stream>>>(betau, root, out);
}

// Round 3
// 526.580 us; speedup vs baseline: 8.5602x; 1.3229x over previous
//
#include <hip/hip_runtime.h>
#include <cstddef>

#define Bv 4
#define Nv 24
#define NTv 16
#define Tv 64
#define NP 25
#define NEGF (-1e30f)

// ---------------- workspace layout (floats) ----------------
#define BETAA_OFF 0         // [B][25][25][16 sym][24 head]            960000
#define BETAU_OFF 960000    // [B][25][25][64 sym]                     160000
#define RNT_OFF   1120000   // [B][2 d][24 h][16 A][16 sL][16 sR]      786432
#define T0_OFF    1906432   // [B][24 h][24 p][16 sL][16 A]            589824
#define T1_OFF    2496256   // [B][24 h][24 p][16 sR][16 A]            589824
#define T0L_OFF   3086080   // [B][24 h][16 sR][16 A]                  24576
#define T1R_OFF   3110656   // [B][24 h][16 sL][16 A]                  24576
#define D0_OFF    3135232   // [B][24 l][16 A]                         1536
#define D1_OFF    3136768   // [B][24 l][16 A]                         1536
#define EU_OFF    3138304   // [B][24 p][48 j]  exp(unary terminal)    4608
#define WS_NEED   3142912

// ---- init: width-1 betau + exp(unary) table ----
__global__ void init_kernel(const float* __restrict__ unary, float* __restrict__ betau,
                            float* __restrict__ Eu) {
  int t = blockIdx.x * blockDim.x + threadIdx.x;
  if (t >= Bv * Nv * 48) return;
  int i = t % 48, kk = (t / 48) % Nv, b = t / (48 * Nv);
  float u = unary[(size_t)(b * Nv + kk) * Tv + 16 + i];
  betau[((size_t)(b * NP + kk) * NP + (kk + 1)) * Tv + 16 + i] = u;
  Eu[(size_t)(b * Nv + kk) * 48 + i] = __expf(u);
}

// ---- fused prep: block per (b,A,h); coalesced 32KB rule read; all precontractions ----
__global__ __launch_bounds__(256) void prep_kernel(
    const float* __restrict__ rule, const float* __restrict__ Eu,
    float* __restrict__ RNT, float* __restrict__ T0, float* __restrict__ T1,
    float* __restrict__ T0L, float* __restrict__ T1R,
    float* __restrict__ D0, float* __restrict__ D1) {
  const int h = blockIdx.x, A = blockIdx.y, b = blockIdx.z;
  const int t = threadIdx.x;  // 256
  __shared__ float er0[64 * 65];  // exp(rule[..,sL,sR,0]), padded rows
  __shared__ float er1[64 * 65];
  __shared__ float E[24 * 48];
  __shared__ float red[256];

  for (int i = t; i < 24 * 48; i += 256) E[i] = Eu[(size_t)b * (24 * 48) + i];
  const float* rb = rule + (size_t)((b * NTv + A) * Nv + h) * 8192;
#pragma unroll
  for (int i = 0; i < 8; ++i) {
    int lin = i * 1024 + t * 4;  // = sL*128 + sR*2 + d
    float4 v = *(const float4*)(rb + lin);
    int sL = lin >> 7, rem = (lin & 127) >> 1;
    er0[sL * 65 + rem] = __expf(v.x);
    er1[sL * 65 + rem] = __expf(v.y);
    er0[sL * 65 + rem + 1] = __expf(v.z);
    er1[sL * 65 + rem + 1] = __expf(v.w);
  }
  __syncthreads();
  // RNT (A-major layout): coalesced 1KB store per d
  {
    float* dst0 = RNT + (((size_t)(b * 2 + 0) * Nv + h) * NTv + A) * 256;
    float* dst1 = RNT + (((size_t)(b * 2 + 1) * Nv + h) * NTv + A) * 256;
    dst0[t] = er0[(t >> 4) * 65 + (t & 15)];
    dst1[t] = er1[(t >> 4) * 65 + (t & 15)];
  }
  // T0[b,h,p,sL,A] = sum_j E[p][j]*er0[sL][16+j]
  for (int o = t; o < 384; o += 256) {
    int p = o >> 4, sL = o & 15;
    const float* Ep = E + p * 48;
    const float* r0 = er0 + sL * 65 + 16;
    float acc = 0.f;
#pragma unroll 8
    for (int j = 0; j < 48; ++j) acc += Ep[j] * r0[j];
    T0[(((size_t)(b * Nv + h) * Nv + p) * NTv + sL) * NTv + A] = acc;
  }
  // T1[b,h,p,sR,A] = sum_i E[p][i]*er1[16+i][sR]
  for (int o = t; o < 384; o += 256) {
    int p = o >> 4, sR = o & 15;
    const float* Ep = E + p * 48;
    float acc = 0.f;
#pragma unroll 8
    for (int i = 0; i < 48; ++i) acc += Ep[i] * er1[(16 + i) * 65 + sR];
    T1[(((size_t)(b * Nv + h) * Nv + p) * NTv + sR) * NTv + A] = acc;
  }
  if (t < 16) {  // T0L[b,h,sR,A] = sum_i er0[16+i][sR]
    float acc = 0.f;
    for (int i = 0; i < 48; ++i) acc += er0[(16 + i) * 65 + t];
    T0L[((size_t)(b * Nv + h) * NTv + t) * NTv + A] = acc;
  } else if (t < 32) {  // T1R[b,h,sL,A] = sum_j er1[sL][16+j]
    int sL = t - 16;
    float acc = 0.f;
    for (int j = 0; j < 48; ++j) acc += er1[sL * 65 + 16 + j];
    T1R[((size_t)(b * Nv + h) * NTv + sL) * NTv + A] = acc;
  }
  // D0[b,l=h,A] = sum_{i,j} E[h+1][j]*er0[16+i][16+j];  D1[b,l=h-1,A] likewise
  float acc0 = 0.f, acc1 = 0.f;
  const int hp = (h + 1 < 24) ? h + 1 : 0, hm = (h >= 1) ? h - 1 : 0;
  for (int e = t; e < 2304; e += 256) {
    int i = e / 48, j = e % 48;
    float r0 = er0[(16 + i) * 65 + 16 + j];
    float r1 = er1[(16 + i) * 65 + 16 + j];
    acc0 += E[hp * 48 + j] * r0;
    acc1 += E[hm * 48 + i] * r1;
  }
  red[t] = acc0;
  __syncthreads();
  if (t < 64) {
    float s = red[t] + red[t + 64] + red[t + 128] + red[t + 192];
#pragma unroll
    for (int off = 32; off; off >>= 1) s += __shfl_xor(s, off, 64);
    if (t == 0 && h <= 22) D0[((size_t)b * Nv + h) * NTv + A] = s;
  }
  __syncthreads();
  red[t] = acc1;
  __syncthreads();
  if (t < 64) {
    float s = red[t] + red[t + 64] + red[t + 128] + red[t + 192];
#pragma unroll
    for (int off = 32; off; off >>= 1) s += __shfl_xor(s, off, 64);
    if (t == 0 && h >= 1) D1[((size_t)b * Nv + (h - 1)) * NTv + A] = s;
  }
}

// online-max outer-product update: lanes 0-15 hold left vals, 16-31 right vals
__device__ __forceinline__ void upd(float a, int k, float& G, float (&U)[8]) {
  float m16 = a;
  m16 = fmaxf(m16, __shfl_xor(m16, 8, 16));
  m16 = fmaxf(m16, __shfl_xor(m16, 4, 16));
  m16 = fmaxf(m16, __shfl_xor(m16, 2, 16));
  m16 = fmaxf(m16, __shfl_xor(m16, 1, 16));
  float other = __shfl_xor(m16, 16, 32);
  float mL = (k < 16) ? m16 : other;
  float mR = (k < 16) ? other : m16;
  float sh = mL + mR;
  float Gn = fmaxf(G, sh);
  float f = __expf(G - Gn);
  float vR = __shfl(a, 16 + (k & 15), 32);
  float vb = vR - Gn;
#pragma unroll
  for (int j = 0; j < 8; ++j) {
    float vL = __shfl(a, 2 * j + (k >> 4), 32);
    U[j] = U[j] * f + __expf(vL + vb);
  }
  G = Gn;
}

__device__ __forceinline__ void edge_dot(float v0, float v1, float v2, float v3,
                                         const float* Tb, float& sh, float& S) {
  float mx = fmaxf(fmaxf(v0, v1), fmaxf(v2, v3));
  mx = fmaxf(mx, __shfl_xor(mx, 1, 64));
  mx = fmaxf(mx, __shfl_xor(mx, 2, 64));
  float dot = __expf(v0 - mx) * Tb[0] + __expf(v1 - mx) * Tb[16] +
              __expf(v2 - mx) * Tb[32] + __expf(v3 - mx) * Tb[48];
  dot += __shfl_xor(dot, 1, 64);
  dot += __shfl_xor(dot, 2, 64);
  sh = mx;
  S = dot;
}

// ---- width kernel: barrier-free Phase A (register U per 32-lane head group) ----
__global__ __launch_bounds__(768) void width_kernel3(
    const float* __restrict__ unary, float* __restrict__ betaA, float* __restrict__ betau,
    const float* __restrict__ RNT, const float* __restrict__ T0, const float* __restrict__ T1,
    const float* __restrict__ T0L, const float* __restrict__ T1R,
    const float* __restrict__ D0, const float* __restrict__ D1, int W) {
  const int l = blockIdx.x, b = blockIdx.y;
  const int r = l + W;
  const int tid = threadIdx.x;

  __shared__ float U0[24 * 256], U1[24 * 256];
  __shared__ float sG0[24], sG1[24];
  __shared__ float cLs[16 * 25], ecRs[16 * 25];  // chart(l,r-1), chart(l+1,r): [s][hh]
  __shared__ float eLs[16], eeRs[16];            // betau(l,r-1), betau(l+1,r) NT part
  __shared__ float pM[2 * 24 * 16], pS[2 * 24 * 16];
  __shared__ float sTmp[16 * 24];

  // ---- edge staging (no barrier needed until Phase B) ----
  if (W >= 3) {
    if (tid < 384) {
      int s = tid / 24, j = tid % 24, jj = j - l;
      float v = betaA[((size_t)(b * NP + l) * NP + (r - 1)) * 384 + s * 24 + j];
      if (jj >= 0 && jj < 24) cLs[s * 25 + jj] = v;
    } else {
      int t2 = tid - 384;
      int s = t2 / 24, j = t2 % 24, jj = j - l;
      float v = betaA[((size_t)(b * NP + (l + 1)) * NP + r) * 384 + s * 24 + j];
      if (jj >= 0 && jj < 24) ecRs[s * 25 + jj] = v;
    }
    if (tid < 16) eLs[tid] = betau[((size_t)(b * NP + l) * NP + (r - 1)) * Tv + tid];
    else if (tid >= 32 && tid < 48)
      eeRs[tid - 32] = betau[((size_t)(b * NP + (l + 1)) * NP + r) * Tv + (tid - 32)];
  }

  // ---- Phase A: per-head register-U accumulation over interior splits ----
  const int g = tid >> 5;   // head offset 0..23
  const int k = tid & 31;   // group lane
  float U0r[8], U1r[8];
#pragma unroll
  for (int j = 0; j < 8; ++j) { U0r[j] = 0.f; U1r[j] = 0.f; }
  float G0 = NEGF, G1 = NEGF;

  if (g < W) {
    const int hcol = l + g;
    // d1 splits: m in [l+2, min(l+g, r-2)]  (head in right child)
    {
      int m = l + 2, mend = min(l + g, r - 2);
      if (m <= mend) {
        const float* src;
        size_t base, stride;
        if (k < 16) {  // left betau(l,m)[k]
          src = betau; base = ((size_t)(b * NP + l) * NP) * Tv + k; stride = Tv;
        } else {       // right chart betaA(m,r)[k-16][hcol]
          src = betaA;
          base = (size_t)(b * NP) * NP * 384 + (size_t)r * 384 + (size_t)(k - 16) * 24 + hcol;
          stride = (size_t)NP * 384;
        }
        float a_next = src[base + (size_t)m * stride];
        for (; m <= mend; ++m) {
          float a = a_next;
          if (m < mend) a_next = src[base + (size_t)(m + 1) * stride];
          upd(a, k, G1, U1r);
        }
      }
    }
    // d0 splits: m in [max(l+g+1, l+2), r-2]  (head in left child)
    {
      int m = max(l + g + 1, l + 2), mend = r - 2;
      if (m <= mend) {
        const float* src;
        size_t base, stride;
        if (k < 16) {  // left chart betaA(l,m)[k][hcol]
          src = betaA;
          base = ((size_t)(b * NP + l) * NP) * 384 + (size_t)k * 24 + hcol;
          stride = 384;
        } else {       // right betau(m,r)[k-16]
          src = betau;
          base = (size_t)(b * NP) * NP * Tv + (size_t)r * Tv + (k - 16);
          stride = (size_t)NP * Tv;
        }
        float a_next = src[base + (size_t)m * stride];
        for (; m <= mend; ++m) {
          float a = a_next;
          if (m < mend) a_next = src[base + (size_t)(m + 1) * stride];
          upd(a, k, G0, U0r);
        }
      }
    }
#pragma unroll
    for (int j = 0; j < 8; ++j) {
      U0[g * 256 + k + 32 * j] = U0r[j];
      U1[g * 256 + k + 32 * j] = U1r[j];
    }
    if (k == 0) { sG0[g] = G0; sG1[g] = G1; }
  }
  __syncthreads();

  // ---- Phase B: per (head,dir) contraction; lane = (A, q) ----
  {
    const int w = tid >> 6, lane = tid & 63;
    const int A = lane >> 2, q = lane & 3;
    for (int p = w; p < 2 * W; p += 12) {
      const int hh = p >> 1, d = p & 1;
      const int h = l + hh;
      const float* Urow = (d ? U1 : U0) + hh * 256 + 4 * q;
      const float* Rb = RNT + (((size_t)(b * 2 + d) * Nv + h) * NTv + A) * 256 + 4 * q;
      float acc = 0.f;
#pragma unroll
      for (int sL = 0; sL < 16; ++sL) {
        float4 u = *(const float4*)(Urow + sL * 16);
        float4 rv = *(const float4*)(Rb + sL * 16);
        acc += u.x * rv.x + u.y * rv.y + u.z * rv.z + u.w * rv.w;
      }
      acc += __shfl_xor(acc, 1, 64);
      acc += __shfl_xor(acc, 2, 64);
      float Mi = d ? sG1[hh] : sG0[hh];
      float sh2 = NEGF, S2 = 0.f, sh3 = NEGF, S3 = 0.f;
      if (W >= 3) {
        if (d == 0) {
          if (hh < W - 1) {  // split m=r-1: chart(l,r-1) x terminal via T0
            const float* Tb = T0 + (((size_t)(b * Nv + h) * Nv + (r - 1)) * NTv + 4 * q) * NTv + A;
            edge_dot(cLs[(4 * q + 0) * 25 + hh], cLs[(4 * q + 1) * 25 + hh],
                     cLs[(4 * q + 2) * 25 + hh], cLs[(4 * q + 3) * 25 + hh], Tb, sh2, S2);
          }
          if (hh == 0) {     // split m=l+1: terminal x betau(l+1,r) via T0L
            const float* Tb = T0L + ((size_t)(b * Nv + l) * NTv + 4 * q) * NTv + A;
            edge_dot(eeRs[4 * q + 0], eeRs[4 * q + 1], eeRs[4 * q + 2], eeRs[4 * q + 3],
                     Tb, sh3, S3);
          }
        } else {
          if (hh >= 1) {     // split m=l+1: terminal x chart(l+1,r) via T1
            const float* Tb = T1 + (((size_t)(b * Nv + h) * Nv + l) * NTv + 4 * q) * NTv + A;
            edge_dot(ecRs[(4 * q + 0) * 25 + hh], ecRs[(4 * q + 1) * 25 + hh],
                     ecRs[(4 * q + 2) * 25 + hh], ecRs[(4 * q + 3) * 25 + hh], Tb, sh2, S2);
          }
          if (hh == W - 1) { // split m=r-1: betau(l,r-1) x terminal via T1R
            const float* Tb = T1R + ((size_t)(b * Nv + (r - 1)) * NTv + 4 * q) * NTv + A;
            edge_dot(eLs[4 * q + 0], eLs[4 * q + 1], eLs[4 * q + 2], eLs[4 * q + 3],
                     Tb, sh3, S3);
          }
        }
      } else {  // W == 2
        if (d == 0 && hh == 0) { sh2 = 0.f; S2 = D0[((size_t)b * Nv + l) * NTv + A]; }
        if (d == 1 && hh == 1) { sh2 = 0.f; S2 = D1[((size_t)b * Nv + l) * NTv + A]; }
      }
      float Mf = fmaxf(Mi, fmaxf(sh2, sh3));
      float Sf = acc * __expf(Mi - Mf) + S2 * __expf(sh2 - Mf) + S3 * __expf(sh3 - Mf);
      if (q == 0) {
        pM[(d * 24 + hh) * 16 + A] = Mf;
        pS[(d * 24 + hh) * 16 + A] = Sf;
      }
    }
  }
  __syncthreads();
  // combine dirs, write betaA; prep betau input
  if (tid < 384) {
    int A2 = tid & 15, hh = tid >> 4;
    if (hh < W) {
      float M0 = pM[(0 * 24 + hh) * 16 + A2], S0 = pS[(0 * 24 + hh) * 16 + A2];
      float M1 = pM[(1 * 24 + hh) * 16 + A2], S1 = pS[(1 * 24 + hh) * 16 + A2];
      float nm = fmaxf(M0, M1);
      float s = S0 * __expf(M0 - nm) + S1 * __expf(M1 - nm);
      float val = nm + __logf(s);
      betaA[((size_t)(b * NP + l) * NP + r) * 384 + A2 * 24 + (l + hh)] = val;
      sTmp[A2 * 24 + hh] = val + unary[(size_t)(b * Nv + (l + hh)) * Tv + A2];
    }
  }
  __syncthreads();
  if (tid < 16) {
    float mx = NEGF;
    for (int x = 0; x < W; ++x) mx = fmaxf(mx, sTmp[tid * 24 + x]);
    float s = 0.f;
    for (int x = 0; x < W; ++x) s += __expf(sTmp[tid * 24 + x] - mx);
    betau[((size_t)(b * NP + l) * NP + r) * Tv + tid] = mx + __logf(s);
  }
}

// ---- fallback width kernel (direct rule reads), used only if ws too small ----
__global__ __launch_bounds__(768) void width_kernel_fb(
    const float* __restrict__ unary, const float* __restrict__ rule,
    float* __restrict__ betaA, float* __restrict__ betau, int W) {
  const int l = blockIdx.x, b = blockIdx.y;
  const int r = l + W;
  const int tid = threadIdx.x;
  const int sub = tid & 1;
  const int pid = tid >> 1;
  const int A = pid & 15;
  const int hh = pid >> 4;
  const int h = l + hh;
  const bool act = (hh < W);
  const int sA = tid & 15, sH = tid >> 4;

  __shared__ float sER0[48], sEL1[48];
  __shared__ float sCL0[16 * 24], sCR1[16 * 24];
  __shared__ float sMaxL0[24], sMaxR1[24];
  __shared__ float sShR0, sShL1;
  __shared__ float sTmp[16 * 24];

  float runM = NEGF, runS = 0.f;
  for (int m = l + 1; m < r; ++m) {
    const int wl = m - l, wr = r - m;
    if (tid < 64) {
      const int n = (wr == 1) ? 48 : 16, s0 = (wr == 1) ? 16 : 0;
      float v = (tid < n) ? betau[(size_t)((b * NP + m) * NP + r) * Tv + s0 + tid] : NEGF;
      float mx = v;
#pragma unroll
      for (int off = 32; off; off >>= 1) mx = fmaxf(mx, __shfl_xor(mx, off, 64));
      if (tid == 0) sShR0 = mx;
      if (tid < n) sER0[tid] = v - mx;
    } else if (tid < 128) {
      const int j = tid - 64;
      const int n = (wl == 1) ? 48 : 16, s0 = (wl == 1) ? 16 : 0;
      float v = (j < n) ? betau[(size_t)((b * NP + l) * NP + m) * Tv + s0 + j] : NEGF;
      float mx = v;
#pragma unroll
      for (int off = 32; off; off >>= 1) mx = fmaxf(mx, __shfl_xor(mx, off, 64));
      if (j == 0) sShL1 = mx;
      if (j < n) sEL1[j] = v - mx;
    }
    if (tid < 384) {
      if (wl > 1 && sH < wl) {
        float v = betaA[(size_t)((b * NP + l) * NP + m) * 384 + sA * Nv + (l + sH)];
        float mx = v;
#pragma unroll
        for (int off = 8; off; off >>= 1) mx = fmaxf(mx, __shfl_xor(mx, off, 16));
        if (sA == 0) sMaxL0[sH] = mx;
        sCL0[sA * Nv + sH] = v - mx;
      }
      if (wr > 1 && sH >= wl && sH < W) {
        float v = betaA[(size_t)((b * NP + m) * NP + r) * 384 + sA * Nv + (l + sH)];
        float mx = v;
#pragma unroll
        for (int off = 8; off; off >>= 1) mx = fmaxf(mx, __shfl_xor(mx, off, 16));
        if (sA == 0) sMaxR1[sH] = mx;
        sCR1[sA * Nv + sH] = v - mx;
      }
    }
    __syncthreads();
    if (act) {
      if (hh < wl && (wl > 1 || hh == 0)) {
        const int nL = (wl == 1) ? 48 : 16, sL0 = (wl == 1) ? 16 : 0;
        const int nR = (wr == 1) ? 48 : 16, sR0 = (wr == 1) ? 16 : 0;
        const float shift = ((wl == 1) ? 0.f : sMaxL0[hh]) + sShR0;
        float part = 0.f;
        const float* rb = rule + (size_t)(((b * NTv + A) * Nv + h) * Tv) * Tv * 2;
        for (int i = sub; i < nL; i += 2) {
          const float cl = (wl == 1) ? 0.f : sCL0[i * Nv + hh];
          const float* rp = rb + (size_t)(sL0 + i) * Tv * 2 + sR0 * 2;
#pragma unroll 8
          for (int j = 0; j < nR; ++j) part += __expf(cl + sER0[j] + rp[j * 2]);
        }
        float nm = fmaxf(runM, shift);
        runS = runS * __expf(runM - nm) + part * __expf(shift - nm);
        runM = nm;
      }
      if (hh >= wl && (wr > 1 || hh == W - 1)) {
        const int nL = (wl == 1) ? 48 : 16, sL0 = (wl == 1) ? 16 : 0;
        const int nR = (wr == 1) ? 48 : 16, sR0 = (wr == 1) ? 16 : 0;
        const float shift = sShL1 + ((wr == 1) ? 0.f : sMaxR1[hh]);
        float part = 0.f;
        const float* rb = rule + (size_t)(((b * NTv + A) * Nv + h) * Tv) * Tv * 2 + 1;
        for (int i = sub; i < nL; i += 2) {
          const float el = sEL1[i];
          const float* rp = rb + (size_t)(sL0 + i) * Tv * 2 + sR0 * 2;
#pragma unroll 8
          for (int j = 0; j < nR; ++j) {
            const float cr = (wr == 1) ? 0.f : sCR1[j * Nv + hh];
            part += __expf(el + cr + rp[j * 2]);
          }
        }
        float nm = fmaxf(runM, shift);
        runS = runS * __expf(runM - nm) + part * __expf(shift - nm);
        runM = nm;
      }
    }
    __syncthreads();
  }
  if (act) {
    float om = __shfl_xor(runM, 1, 64);
    float os = __shfl_xor(runS, 1, 64);
    float nm = fmaxf(runM, om);
    float s = runS * __expf(runM - nm) + os * __expf(om - nm);
    if (sub == 0) {
      float val = nm + __logf(s);
      betaA[(size_t)((b * NP + l) * NP + r) * 384 + A * Nv + h] = val;
      sTmp[A * Nv + hh] = val + unary[(b * Nv + h) * Tv + A];
    }
  }
  __syncthreads();
  if (tid < 16) {
    float mx = NEGF;
    for (int x = 0; x < W; ++x) mx = fmaxf(mx, sTmp[tid * Nv + x]);
    float s = 0.f;
    for (int x = 0; x < W; ++x) s += __expf(sTmp[tid * Nv + x] - mx);
    betau[(size_t)((b * NP + l) * NP + r) * Tv + tid] = mx + __logf(s);
  }
}

__global__ void final_kernel(const float* __restrict__ betau, const float* __restrict__ root,
                             float* __restrict__ out) {
  int b = threadIdx.x;
  if (b < Bv) {
    float vals[NTv];
    float mx = NEGF;
#pragma unroll
    for (int A = 0; A < NTv; ++A) {
      float v = betau[(size_t)((b * NP + 0) * NP + Nv) * Tv + A] + root[b * NTv + A];
      vals[A] = v;
      mx = fmaxf(mx, v);
    }
    float s = 0.f;
#pragma unroll
    for (int A = 0; A < NTv; ++A) s += __expf(vals[A] - mx);
    out[b] = mx + __logf(s);
  }
}

extern "C" void kernel_launch(void* const* d_in, const int* in_sizes, int n_in,
                              void* d_out, int out_size, void* d_ws, size_t ws_size,
                              hipStream_t stream) {
  (void)in_sizes; (void)n_in; (void)out_size;
  const float* unary = (const float*)d_in[0];
  const float* rule  = (const float*)d_in[1];
  const float* root  = (const float*)d_in[2];
  float* out = (float*)d_out;
  float* ws = (float*)d_ws;
  float* betaA = ws + BETAA_OFF;
  float* betau = ws + BETAU_OFF;
  const bool fast = ws_size >= (size_t)WS_NEED * sizeof(float);

  if (fast) {
    float* RNT = ws + RNT_OFF;
    float* T0  = ws + T0_OFF;
    float* T1  = ws + T1_OFF;
    float* T0L = ws + T0L_OFF;
    float* T1R = ws + T1R_OFF;
    float* D0  = ws + D0_OFF;
    float* D1  = ws + D1_OFF;
    float* Eu  = ws + EU_OFF;
    init_kernel<<<(Bv * Nv * 48 + 255) / 256, 256, 0, stream>>>(unary, betau, Eu);
    prep_kernel<<<dim3(24, 16, 4), 256, 0, stream>>>(rule, Eu, RNT, T0, T1, T0L, T1R, D0, D1);
    for (int W = 2; W <= Nv; ++W) {
      dim3 grid(Nv - W + 1, Bv);
      width_kernel3<<<grid, 768, 0, stream>>>(unary, betaA, betau, RNT, T0, T1, T0L, T1R, D0, D1, W);
    }
  } else {
    float* Eu = ws + BETAU_OFF + 160000;  // reuse space past betau for Eu in fallback
    init_kernel<<<(Bv * Nv * 48 + 255) / 256, 256, 0, stream>>>(unary, betau, Eu);
    for (int W = 2; W <= Nv; ++W) {
      dim3 grid(Nv - W + 1, Bv);
      width_kernel_fb<<<grid, 768, 0, stream>>>(unary, rule, betaA, betau, W);
    }
  }
  final_kernel<<<1, 64, 0, stream>>>(betau, root, out);
}